// Round 15
// baseline (98.147 us; speedup 1.0000x reference)
//
#include <hip/hip_runtime.h>
#include <hip/hip_bf16.h>

#define NN 50000
#define NE 800000
#define NG 512
#define NB 196            // coarse buckets: dst>>8, 256 nodes each
#define B1_CHUNK 2048
#define B1_BLOCKS ((NE + B1_CHUNK - 1) / B1_CHUNK)   // 391
#define CAP 5120          // LDS cache capacity for a bucket's src list
#define NPB2 84           // nodes per block in gather_fin2_pool (252 = 84*3 threads)

typedef unsigned int uint32;
typedef unsigned short ushort16;

// ---------------- K1: hist (0..390) + fold (391..404) + gstart (405..600) + zero accg (601..624)
__global__ void prep_kernel(const int* __restrict__ dst, int* __restrict__ hist_mat,
                            const float* __restrict__ W1a, const float* __restrict__ b1a,
                            const float* __restrict__ W1b, const float* __restrict__ b1b,
                            const float* __restrict__ W2a, const float* __restrict__ b2a,
                            const float* __restrict__ W2b, const float* __restrict__ b2b,
                            float* __restrict__ W1eff, float* __restrict__ b1eff,
                            float* __restrict__ W2eff, float* __restrict__ b2eff,
                            const int* __restrict__ gid, int* __restrict__ gstart,
                            float* __restrict__ accg) {
    int bid = blockIdx.x;
    int tid = threadIdx.x;
    if (bid < B1_BLOCKS) {
        __shared__ int hist[NB];
        for (int i = tid; i < NB; i += 256) hist[i] = 0;
        __syncthreads();
        int e0 = bid * B1_CHUNK;
        #pragma unroll
        for (int k = 0; k < 8; ++k) {
            int e = e0 + tid + k * 256;
            if (e < NE) atomicAdd(&hist[dst[e] >> 8], 1);
        }
        __syncthreads();
        int* row = hist_mat + bid * NB;
        for (int i = tid; i < NB; i += 256) row[i] = hist[i];
    } else if (bid < B1_BLOCKS + 14) {
        int t = (bid - B1_BLOCKS) * 256 + tid;
        if (t < 3072) {
            int r = t / 12, c = t % 12;
            float acc = 0.f;
            for (int k = 0; k < 256; ++k) acc += W1a[r*256 + k] * W1b[k*12 + c];
            W1eff[r*12 + c] = acc;
        } else if (t < 3084) {
            int c = t - 3072;
            float acc = b1b[c];
            for (int k = 0; k < 256; ++k) acc += b1a[k] * W1b[k*12 + c];
            b1eff[c] = acc;
        } else if (t < 3372) {
            int u = t - 3084;
            int r = u / 12, c = u % 12;
            float acc = 0.f;
            for (int k = 0; k < 256; ++k) acc += W2a[r*256 + k] * W2b[k*12 + c];
            W2eff[r*12 + c] = acc;
        } else if (t < 3384) {
            int c = t - 3372;
            float acc = b2b[c];
            for (int k = 0; k < 256; ++k) acc += b2a[k] * W2b[k*12 + c];
            b2eff[c] = acc;
        }
    } else if (bid < B1_BLOCKS + 14 + 196) {
        int n = (bid - B1_BLOCKS - 14) * 256 + tid;
        if (n < NN) {
            int cur = gid[n];
            int prev = (n == 0) ? -1 : gid[n - 1];
            for (int g = prev + 1; g <= cur; ++g) gstart[g] = n;
            if (n == NN - 1) {
                for (int g = cur + 1; g <= NG; ++g) gstart[g] = NN;
            }
        }
    } else {
        int t = (bid - B1_BLOCKS - 14 - 196) * 256 + tid;
        if (t < NG * 12) accg[t] = 0.f;
    }
}

// ---------------- K2: offs scan (bucket bid) then p1 for nodes bid*768+tid -----
__global__ void __launch_bounds__(768) offsp1_kernel(
    const int* __restrict__ hist_mat, int* __restrict__ off_mat, int* __restrict__ btot,
    const float* __restrict__ h, const float* __restrict__ W1eff,
    float* __restrict__ p1t, float* __restrict__ p1b) {
    __shared__ int sh[512];
    int tid = threadIdx.x;   // 768
    int b = blockIdx.x;      // 196 == NB
    int v = 0;
    if (tid < 512) {
        v = (tid < B1_BLOCKS) ? hist_mat[tid * NB + b] : 0;
        sh[tid] = v;
    }
    __syncthreads();
    for (int off = 1; off < 512; off <<= 1) {
        int t2 = (tid < 512 && tid >= off) ? sh[tid - off] : 0;
        __syncthreads();
        if (tid < 512) sh[tid] += t2;
        __syncthreads();
    }
    if (tid < B1_BLOCKS) off_mat[tid * NB + b] = sh[tid] - v;   // local exclusive
    if (tid == B1_BLOCKS - 1) btot[b] = sh[tid];                // bucket total
    int n = b * 768 + tid;
    if (n >= NN) return;
    const float4* hrow = (const float4*)(h + (size_t)n * 128);
    float acc[24];
    #pragma unroll
    for (int j = 0; j < 24; ++j) acc[j] = 0.f;
    #pragma unroll 4
    for (int kq = 0; kq < 32; ++kq) {
        float4 hv = hrow[kq];
        #pragma unroll
        for (int u = 0; u < 4; ++u) {
            int k = kq * 4 + u;
            float hx = u == 0 ? hv.x : (u == 1 ? hv.y : (u == 2 ? hv.z : hv.w));
            const float4* wt = (const float4*)(W1eff + k * 12);
            const float4* wb = (const float4*)(W1eff + (128 + k) * 12);
            #pragma unroll
            for (int q = 0; q < 3; ++q) {
                float4 a = wt[q];
                float4 bq = wb[q];
                acc[q*4 + 0]      += hx * a.x;
                acc[q*4 + 1]      += hx * a.y;
                acc[q*4 + 2]      += hx * a.z;
                acc[q*4 + 3]      += hx * a.w;
                acc[12 + q*4 + 0] += hx * bq.x;
                acc[12 + q*4 + 1] += hx * bq.y;
                acc[12 + q*4 + 2] += hx * bq.z;
                acc[12 + q*4 + 3] += hx * bq.w;
            }
        }
    }
    float* pt = p1t + (size_t)n * 12;
    float* pb = p1b + (size_t)n * 12;
    #pragma unroll
    for (int c = 0; c < 12; ++c) pt[c] = acc[c];
    #pragma unroll
    for (int c = 0; c < 12; ++c) pb[c] = acc[12 + c];
}

// ---------------- K3: place packed (src<<8|ln) into coarse bucket regions ------
__global__ void place_pairs_kernel(const int* __restrict__ src, const int* __restrict__ dst,
                                   const int* __restrict__ off_mat, const int* __restrict__ btot,
                                   uint32* __restrict__ pairs) {
    __shared__ int sb[256];
    __shared__ int lbase[NB];
    __shared__ int lcur[NB];
    int tid = threadIdx.x;   // 256
    int v = (tid < NB) ? btot[tid] : 0;
    sb[tid] = v;
    __syncthreads();
    for (int off = 1; off < 256; off <<= 1) {
        int t = (tid >= off) ? sb[tid - off] : 0;
        __syncthreads();
        sb[tid] += t;
        __syncthreads();
    }
    const int* orow = off_mat + blockIdx.x * NB;
    if (tid < NB) {
        lbase[tid] = (sb[tid] - v) + orow[tid];   // bucket_base + local offset
        lcur[tid] = 0;
    }
    __syncthreads();
    int e0 = blockIdx.x * B1_CHUNK;
    #pragma unroll
    for (int k = 0; k < 8; ++k) {
        int e = e0 + tid + k * 256;
        if (e < NE) {
            int dd = dst[e];
            int ss = src[e];
            int bb = dd >> 8;
            int idx = atomicAdd(&lcur[bb], 1);
            pairs[lbase[bb] + idx] = ((uint32)ss << 8) | (uint32)(dd & 255);
        }
    }
}

// ---------------- K4: per-bucket sort + gather(p1b) + finalize1 ----------------
__global__ void fine_gf1_kernel(const uint32* __restrict__ pairs, const int* __restrict__ btot,
                                const float* __restrict__ p1t, const float* __restrict__ p1b,
                                const float* __restrict__ b1eff, const float* __restrict__ W2eff,
                                int* __restrict__ row_start, ushort16* __restrict__ sorted_src,
                                float* __restrict__ p2t, float* __restrict__ p2b) {
    __shared__ int sb[256];
    __shared__ int cnt[256];
    __shared__ int sc[256];
    __shared__ int rs[257];
    __shared__ float hacc[256 * 13];
    __shared__ float w2[288];
    __shared__ float b1[12];
    __shared__ ushort16 ssrc[CAP];
    int tid = threadIdx.x;   // 768
    int b = blockIdx.x;
    if (tid < 256) { sb[tid] = (tid < NB) ? btot[tid] : 0; cnt[tid] = 0; }
    for (int i = tid; i < 288; i += 768) w2[i] = W2eff[i];
    if (tid >= 256 && tid < 268) b1[tid - 256] = b1eff[tid - 256];
    __syncthreads();
    for (int off = 1; off < 256; off <<= 1) {
        int t = (tid < 256 && tid >= off) ? sb[tid - off] : 0;
        __syncthreads();
        if (tid < 256) sb[tid] += t;
        __syncthreads();
    }
    int vb = btot[b];
    int R0 = sb[b] - vb, R1 = R0 + vb;
    bool use_lds = (vb <= CAP);
    for (int i = R0 + tid; i < R1; i += 768)
        atomicAdd(&cnt[(int)(pairs[i] & 255u)], 1);
    __syncthreads();
    if (tid < 256) sc[tid] = cnt[tid];
    __syncthreads();
    for (int off = 1; off < 256; off <<= 1) {
        int t = (tid < 256 && tid >= off) ? sc[tid - off] : 0;
        __syncthreads();
        if (tid < 256) sc[tid] += t;
        __syncthreads();
    }
    if (tid < 256) rs[tid] = R0 + sc[tid] - cnt[tid];
    if (tid == 255) rs[256] = R0 + sc[255];
    __syncthreads();
    if (tid < 256) cnt[tid] = 0;   // placement cursors
    int n0 = b << 8;
    int nloc = min(256, NN - n0);
    if (tid < nloc) row_start[n0 + tid] = rs[tid];
    if (b == NB - 1 && tid == 0) row_start[NN] = R1;
    __syncthreads();
    for (int i = R0 + tid; i < R1; i += 768) {
        uint32 pr = pairs[i];
        int ln = (int)(pr & 255u);
        int ss = (int)(pr >> 8);
        int off2 = atomicAdd(&cnt[ln], 1);
        int pos = rs[ln] + off2;
        sorted_src[pos] = (ushort16)ss;
        if (use_lds) ssrc[pos - R0] = (ushort16)ss;
    }
    __syncthreads();
    {
        int li = tid / 3, q = tid - li * 3;   // li in [0,256)
        int r0 = rs[li], r1 = rs[li + 1];
        float4 s = make_float4(0.f, 0.f, 0.f, 0.f);
        if (use_lds) {
            for (int i = r0 - R0; i < r1 - R0; ++i) {
                int sn = (int)ssrc[i];
                float4 v = ((const float4*)(p1b + (size_t)sn * 12))[q];
                s.x += v.x; s.y += v.y; s.z += v.z; s.w += v.w;
            }
        } else {
            for (int i = r0; i < r1; ++i) {
                int sn = (int)sorted_src[i];
                float4 v = ((const float4*)(p1b + (size_t)sn * 12))[q];
                s.x += v.x; s.y += v.y; s.z += v.z; s.w += v.w;
            }
        }
        float* hp = &hacc[li * 13 + q * 4];
        hp[0] = s.x; hp[1] = s.y; hp[2] = s.z; hp[3] = s.w;
    }
    __syncthreads();
    int n = n0 + tid;
    if (tid < 256 && n < NN) {
        int dg = rs[tid + 1] - rs[tid];
        float inv = dg > 0 ? 1.f / (float)dg : 0.f;
        const float4* ptp = (const float4*)(p1t + (size_t)n * 12);
        float4 a0 = ptp[0], a1 = ptp[1], a2 = ptp[2];
        float pt[12] = {a0.x,a0.y,a0.z,a0.w, a1.x,a1.y,a1.z,a1.w, a2.x,a2.y,a2.z,a2.w};
        float h1[12];
        #pragma unroll
        for (int j = 0; j < 12; ++j) {
            float v = pt[j] + hacc[tid * 13 + j] * inv + b1[j];
            h1[j] = v > 0.f ? v : 0.f;
        }
        float oa[12], ob[12];
        #pragma unroll
        for (int co = 0; co < 12; ++co) {
            float A = 0.f, B = 0.f;
            #pragma unroll
            for (int k = 0; k < 12; ++k) {
                A += h1[k] * w2[k*12 + co];
                B += h1[k] * w2[(12+k)*12 + co];
            }
            oa[co] = A; ob[co] = B;
        }
        float4* ot = (float4*)(p2t + (size_t)n * 12);
        float4* ou = (float4*)(p2b + (size_t)n * 12);
        ot[0] = make_float4(oa[0],oa[1],oa[2],oa[3]);
        ot[1] = make_float4(oa[4],oa[5],oa[6],oa[7]);
        ot[2] = make_float4(oa[8],oa[9],oa[10],oa[11]);
        ou[0] = make_float4(ob[0],ob[1],ob[2],ob[3]);
        ou[1] = make_float4(ob[4],ob[5],ob[6],ob[7]);
        ou[2] = make_float4(ob[8],ob[9],ob[10],ob[11]);
    }
}

// ---------------- K5: gather2 + finalize2 + per-block graph partial pooling ----
// 252 active threads = 84 nodes x 3 quads. Nodes are sorted by graph_id, so a
// block spans ~2 graph segments; 12 channel-threads emit one atomicAdd per
// (segment, channel) -> ~16k low-contention atomics total.
__global__ void gather_fin2_pool_kernel(const int* __restrict__ row_start,
                                        const ushort16* __restrict__ sorted_src,
                                        const float* __restrict__ p2t, const float* __restrict__ p2b,
                                        const float* __restrict__ b2eff, const int* __restrict__ gid,
                                        float* __restrict__ accg) {
    __shared__ float poolv[NPB2 * 13];
    __shared__ int gidl[NPB2];
    int tid = threadIdx.x;   // 256, 252 active in compute
    int n0 = blockIdx.x * NPB2;
    if (tid < 252) {
        int li = tid / 3, q = tid - li * 3;
        int n = n0 + li;
        if (n < NN) {
            if (q == 0) gidl[li] = gid[n];
            int r0 = row_start[n], r1 = row_start[n + 1];
            float4 s = make_float4(0.f, 0.f, 0.f, 0.f);
            if (r0 < r1) {
                int sn = (int)sorted_src[r0];             // software-pipelined index
                for (int i = r0 + 1; i < r1; ++i) {
                    int sn_next = (int)sorted_src[i];
                    float4 v = ((const float4*)(p2b + (size_t)sn * 12))[q];
                    s.x += v.x; s.y += v.y; s.z += v.z; s.w += v.w;
                    sn = sn_next;
                }
                float4 v = ((const float4*)(p2b + (size_t)sn * 12))[q];
                s.x += v.x; s.y += v.y; s.z += v.z; s.w += v.w;
            }
            float inv = (r1 > r0) ? 1.f / (float)(r1 - r0) : 0.f;
            float4 pt = ((const float4*)(p2t + (size_t)n * 12))[q];
            const float* b2 = b2eff + q * 4;
            float* pp = &poolv[li * 13 + q * 4];
            float o0 = pt.x + s.x * inv + b2[0];
            float o1 = pt.y + s.y * inv + b2[1];
            float o2 = pt.z + s.z * inv + b2[2];
            float o3 = pt.w + s.w * inv + b2[3];
            pp[0] = o0 > 0.f ? o0 : 0.f;
            pp[1] = o1 > 0.f ? o1 : 0.f;
            pp[2] = o2 > 0.f ? o2 : 0.f;
            pp[3] = o3 > 0.f ? o3 : 0.f;
        } else if (q == 0) {
            gidl[li] = -1;
        }
    }
    __syncthreads();
    if (tid < 12) {
        int ch = tid;
        int curg = gidl[0];
        float sum = poolv[ch];
        for (int li = 1; li < NPB2; ++li) {
            int g2 = gidl[li];
            if (g2 == curg) {
                sum += poolv[li * 13 + ch];
            } else {
                if (curg >= 0) atomicAdd(&accg[curg * 12 + ch], sum);
                curg = g2;
                if (g2 < 0) break;
                sum = poolv[li * 13 + ch];
            }
        }
        if (curg >= 0) atomicAdd(&accg[curg * 12 + ch], sum);
    }
}

// ---------------- K6: out[g][cls] = (accg[g]/cnt[g]) @ Wc + bc -----------------
__global__ void out_kernel(const float* __restrict__ accg, const int* __restrict__ gstart,
                           const float* __restrict__ Wc, const float* __restrict__ bc,
                           float* __restrict__ out) {
    int t = blockIdx.x * blockDim.x + threadIdx.x;
    if (t >= NG * 10) return;
    int g = t / 10, cls = t - g * 10;
    int cn = gstart[g + 1] - gstart[g];
    float inv = cn > 0 ? 1.f / (float)cn : 0.f;
    float o = bc[cls];
    #pragma unroll
    for (int j = 0; j < 12; ++j) o += accg[g*12 + j] * inv * Wc[j*10 + cls];
    out[t] = o;
}

extern "C" void kernel_launch(void* const* d_in, const int* in_sizes, int n_in,
                              void* d_out, int out_size, void* d_ws, size_t ws_size,
                              hipStream_t stream) {
    const float* h   = (const float*)d_in[0];
    const int* src   = (const int*)d_in[1];
    const int* dst   = (const int*)d_in[2];
    const int* gid   = (const int*)d_in[3];
    const float* W1a = (const float*)d_in[4];
    const float* b1a = (const float*)d_in[5];
    const float* W1b = (const float*)d_in[6];
    const float* b1b = (const float*)d_in[7];
    const float* W2a = (const float*)d_in[8];
    const float* b2a = (const float*)d_in[9];
    const float* W2b = (const float*)d_in[10];
    const float* b2b = (const float*)d_in[11];
    const float* Wc  = (const float*)d_in[12];
    const float* bc  = (const float*)d_in[13];
    float* out = (float*)d_out;

    float* ws = (float*)d_ws;
    float* W1eff = ws;                          // 3072
    float* b1eff = ws + 3072;                   // 12
    float* W2eff = ws + 3084;                   // 288
    float* b2eff = ws + 3372;                   // 12
    float* p1t   = ws + 1000000;                // 600000
    float* p1b   = ws + 1600000;                // 600000
    float* p2t   = ws + 2200000;                // 600000
    float* p2b   = ws + 2800000;                // 600000
    float* accg  = ws + 3400000;                // 6144
    uint32* pairs = (uint32*)(ws + 4000000);    // 800000 x 4B
    int*   hist_mat   = (int*)(ws + 4800000);   // 76636
    int*   off_mat    = (int*)(ws + 4880000);   // 76636
    ushort16* sorted_src = (ushort16*)(ws + 4960000);  // 800000 x 2B
    int*   row_start  = (int*)(ws + 5360000);   // 50001
    int*   btot       = (int*)(ws + 5420000);   // 196
    int*   gstart     = (int*)(ws + 5424000);   // 513  -> total ~21.7 MB

    prep_kernel<<<B1_BLOCKS + 14 + 196 + 24, 256, 0, stream>>>(
        dst, hist_mat, W1a, b1a, W1b, b1b, W2a, b2a, W2b, b2b,
        W1eff, b1eff, W2eff, b2eff, gid, gstart, accg);

    offsp1_kernel<<<NB, 768, 0, stream>>>(hist_mat, off_mat, btot, h, W1eff, p1t, p1b);

    place_pairs_kernel<<<B1_BLOCKS, 256, 0, stream>>>(src, dst, off_mat, btot, pairs);

    fine_gf1_kernel<<<NB, 768, 0, stream>>>(pairs, btot, p1t, p1b, b1eff, W2eff,
                                            row_start, sorted_src, p2t, p2b);

    gather_fin2_pool_kernel<<<(NN + NPB2 - 1) / NPB2, 256, 0, stream>>>(
        row_start, sorted_src, p2t, p2b, b2eff, gid, accg);

    out_kernel<<<(NG * 10 + 255) / 256, 256, 0, stream>>>(accg, gstart, Wc, bc, out);
}

// Round 16
// 90.267 us; speedup vs baseline: 1.0873x; 1.0873x over previous
//
#include <hip/hip_runtime.h>
#include <hip/hip_bf16.h>

#define NN 50000
#define NE 800000
#define NG 512
#define NB 196            // coarse buckets: dst>>8, 256 nodes each
#define B1_CHUNK 2048
#define B1_BLOCKS ((NE + B1_CHUNK - 1) / B1_CHUNK)   // 391
#define CAP 5120          // LDS cache capacity for a bucket's src list

typedef unsigned int uint32;
typedef unsigned short ushort16;

// ---------------- K1: fused hist (0..390) + fold (391..404) + gstart (405..600)
__global__ void prep_kernel(const int* __restrict__ dst, int* __restrict__ hist_mat,
                            const float* __restrict__ W1a, const float* __restrict__ b1a,
                            const float* __restrict__ W1b, const float* __restrict__ b1b,
                            const float* __restrict__ W2a, const float* __restrict__ b2a,
                            const float* __restrict__ W2b, const float* __restrict__ b2b,
                            float* __restrict__ W1eff, float* __restrict__ b1eff,
                            float* __restrict__ W2eff, float* __restrict__ b2eff,
                            const int* __restrict__ gid, int* __restrict__ gstart) {
    int bid = blockIdx.x;
    int tid = threadIdx.x;
    if (bid < B1_BLOCKS) {
        __shared__ int hist[NB];
        for (int i = tid; i < NB; i += 256) hist[i] = 0;
        __syncthreads();
        int e0 = bid * B1_CHUNK;
        #pragma unroll
        for (int k = 0; k < 8; ++k) {
            int e = e0 + tid + k * 256;
            if (e < NE) atomicAdd(&hist[dst[e] >> 8], 1);
        }
        __syncthreads();
        int* row = hist_mat + bid * NB;
        for (int i = tid; i < NB; i += 256) row[i] = hist[i];
    } else if (bid < B1_BLOCKS + 14) {
        int t = (bid - B1_BLOCKS) * 256 + tid;
        if (t < 3072) {
            int r = t / 12, c = t % 12;
            float acc = 0.f;
            for (int k = 0; k < 256; ++k) acc += W1a[r*256 + k] * W1b[k*12 + c];
            W1eff[r*12 + c] = acc;
        } else if (t < 3084) {
            int c = t - 3072;
            float acc = b1b[c];
            for (int k = 0; k < 256; ++k) acc += b1a[k] * W1b[k*12 + c];
            b1eff[c] = acc;
        } else if (t < 3372) {
            int u = t - 3084;
            int r = u / 12, c = u % 12;
            float acc = 0.f;
            for (int k = 0; k < 256; ++k) acc += W2a[r*256 + k] * W2b[k*12 + c];
            W2eff[r*12 + c] = acc;
        } else if (t < 3384) {
            int c = t - 3372;
            float acc = b2b[c];
            for (int k = 0; k < 256; ++k) acc += b2a[k] * W2b[k*12 + c];
            b2eff[c] = acc;
        }
    } else {
        int n = (bid - B1_BLOCKS - 14) * 256 + tid;
        if (n < NN) {
            int cur = gid[n];
            int prev = (n == 0) ? -1 : gid[n - 1];
            for (int g = prev + 1; g <= cur; ++g) gstart[g] = n;
            if (n == NN - 1) {
                for (int g = cur + 1; g <= NG; ++g) gstart[g] = NN;
            }
        }
    }
}

// ---------------- K2: offs scan (bucket bid) then p1 for nodes bid*768+tid -----
__global__ void __launch_bounds__(768) offsp1_kernel(
    const int* __restrict__ hist_mat, int* __restrict__ off_mat, int* __restrict__ btot,
    const float* __restrict__ h, const float* __restrict__ W1eff,
    float* __restrict__ p1t, float* __restrict__ p1b) {
    __shared__ int sh[512];
    int tid = threadIdx.x;   // 768
    int b = blockIdx.x;      // 196 == NB
    int v = 0;
    if (tid < 512) {
        v = (tid < B1_BLOCKS) ? hist_mat[tid * NB + b] : 0;
        sh[tid] = v;
    }
    __syncthreads();
    for (int off = 1; off < 512; off <<= 1) {
        int t2 = (tid < 512 && tid >= off) ? sh[tid - off] : 0;
        __syncthreads();
        if (tid < 512) sh[tid] += t2;
        __syncthreads();
    }
    if (tid < B1_BLOCKS) off_mat[tid * NB + b] = sh[tid] - v;   // local exclusive
    if (tid == B1_BLOCKS - 1) btot[b] = sh[tid];                // bucket total
    int n = b * 768 + tid;
    if (n >= NN) return;
    const float4* hrow = (const float4*)(h + (size_t)n * 128);
    float acc[24];
    #pragma unroll
    for (int j = 0; j < 24; ++j) acc[j] = 0.f;
    #pragma unroll 4
    for (int kq = 0; kq < 32; ++kq) {
        float4 hv = hrow[kq];
        #pragma unroll
        for (int u = 0; u < 4; ++u) {
            int k = kq * 4 + u;
            float hx = u == 0 ? hv.x : (u == 1 ? hv.y : (u == 2 ? hv.z : hv.w));
            const float4* wt = (const float4*)(W1eff + k * 12);
            const float4* wb = (const float4*)(W1eff + (128 + k) * 12);
            #pragma unroll
            for (int q = 0; q < 3; ++q) {
                float4 a = wt[q];
                float4 bq = wb[q];
                acc[q*4 + 0]      += hx * a.x;
                acc[q*4 + 1]      += hx * a.y;
                acc[q*4 + 2]      += hx * a.z;
                acc[q*4 + 3]      += hx * a.w;
                acc[12 + q*4 + 0] += hx * bq.x;
                acc[12 + q*4 + 1] += hx * bq.y;
                acc[12 + q*4 + 2] += hx * bq.z;
                acc[12 + q*4 + 3] += hx * bq.w;
            }
        }
    }
    float* pt = p1t + (size_t)n * 12;
    float* pb = p1b + (size_t)n * 12;
    #pragma unroll
    for (int c = 0; c < 12; ++c) pt[c] = acc[c];
    #pragma unroll
    for (int c = 0; c < 12; ++c) pb[c] = acc[12 + c];
}

// ---------------- K3: place packed (src<<8|ln) into coarse bucket regions ------
__global__ void place_pairs_kernel(const int* __restrict__ src, const int* __restrict__ dst,
                                   const int* __restrict__ off_mat, const int* __restrict__ btot,
                                   uint32* __restrict__ pairs) {
    __shared__ int sb[256];
    __shared__ int lbase[NB];
    __shared__ int lcur[NB];
    int tid = threadIdx.x;   // 256
    int v = (tid < NB) ? btot[tid] : 0;
    sb[tid] = v;
    __syncthreads();
    for (int off = 1; off < 256; off <<= 1) {
        int t = (tid >= off) ? sb[tid - off] : 0;
        __syncthreads();
        sb[tid] += t;
        __syncthreads();
    }
    const int* orow = off_mat + blockIdx.x * NB;
    if (tid < NB) {
        lbase[tid] = (sb[tid] - v) + orow[tid];   // bucket_base + local offset
        lcur[tid] = 0;
    }
    __syncthreads();
    int e0 = blockIdx.x * B1_CHUNK;
    #pragma unroll
    for (int k = 0; k < 8; ++k) {
        int e = e0 + tid + k * 256;
        if (e < NE) {
            int dd = dst[e];
            int ss = src[e];
            int bb = dd >> 8;
            int idx = atomicAdd(&lcur[bb], 1);
            pairs[lbase[bb] + idx] = ((uint32)ss << 8) | (uint32)(dd & 255);
        }
    }
}

// ---------------- K4: per-bucket sort + gather(p1b) + finalize1 ----------------
__global__ void fine_gf1_kernel(const uint32* __restrict__ pairs, const int* __restrict__ btot,
                                const float* __restrict__ p1t, const float* __restrict__ p1b,
                                const float* __restrict__ b1eff, const float* __restrict__ W2eff,
                                int* __restrict__ row_start, ushort16* __restrict__ sorted_src,
                                float* __restrict__ p2t, float* __restrict__ p2b) {
    __shared__ int sb[256];
    __shared__ int cnt[256];
    __shared__ int sc[256];
    __shared__ int rs[257];
    __shared__ float hacc[256 * 13];
    __shared__ float w2[288];
    __shared__ float b1[12];
    __shared__ ushort16 ssrc[CAP];
    int tid = threadIdx.x;   // 768
    int b = blockIdx.x;
    if (tid < 256) { sb[tid] = (tid < NB) ? btot[tid] : 0; cnt[tid] = 0; }
    for (int i = tid; i < 288; i += 768) w2[i] = W2eff[i];
    if (tid >= 256 && tid < 268) b1[tid - 256] = b1eff[tid - 256];
    __syncthreads();
    for (int off = 1; off < 256; off <<= 1) {
        int t = (tid < 256 && tid >= off) ? sb[tid - off] : 0;
        __syncthreads();
        if (tid < 256) sb[tid] += t;
        __syncthreads();
    }
    int vb = btot[b];
    int R0 = sb[b] - vb, R1 = R0 + vb;
    bool use_lds = (vb <= CAP);
    for (int i = R0 + tid; i < R1; i += 768)
        atomicAdd(&cnt[(int)(pairs[i] & 255u)], 1);
    __syncthreads();
    if (tid < 256) sc[tid] = cnt[tid];
    __syncthreads();
    for (int off = 1; off < 256; off <<= 1) {
        int t = (tid < 256 && tid >= off) ? sc[tid - off] : 0;
        __syncthreads();
        if (tid < 256) sc[tid] += t;
        __syncthreads();
    }
    if (tid < 256) rs[tid] = R0 + sc[tid] - cnt[tid];
    if (tid == 255) rs[256] = R0 + sc[255];
    __syncthreads();
    if (tid < 256) cnt[tid] = 0;   // placement cursors
    int n0 = b << 8;
    int nloc = min(256, NN - n0);
    if (tid < nloc) row_start[n0 + tid] = rs[tid];
    if (b == NB - 1 && tid == 0) row_start[NN] = R1;
    __syncthreads();
    for (int i = R0 + tid; i < R1; i += 768) {
        uint32 pr = pairs[i];
        int ln = (int)(pr & 255u);
        int ss = (int)(pr >> 8);
        int off2 = atomicAdd(&cnt[ln], 1);
        int pos = rs[ln] + off2;
        sorted_src[pos] = (ushort16)ss;
        if (use_lds) ssrc[pos - R0] = (ushort16)ss;
    }
    __syncthreads();
    {
        int li = tid / 3, q = tid - li * 3;   // li in [0,256)
        int r0 = rs[li], r1 = rs[li + 1];
        float4 s = make_float4(0.f, 0.f, 0.f, 0.f);
        if (use_lds) {
            for (int i = r0 - R0; i < r1 - R0; ++i) {
                int sn = (int)ssrc[i];
                float4 v = ((const float4*)(p1b + (size_t)sn * 12))[q];
                s.x += v.x; s.y += v.y; s.z += v.z; s.w += v.w;
            }
        } else {
            for (int i = r0; i < r1; ++i) {
                int sn = (int)sorted_src[i];
                float4 v = ((const float4*)(p1b + (size_t)sn * 12))[q];
                s.x += v.x; s.y += v.y; s.z += v.z; s.w += v.w;
            }
        }
        float* hp = &hacc[li * 13 + q * 4];
        hp[0] = s.x; hp[1] = s.y; hp[2] = s.z; hp[3] = s.w;
    }
    __syncthreads();
    int n = n0 + tid;
    if (tid < 256 && n < NN) {
        int dg = rs[tid + 1] - rs[tid];
        float inv = dg > 0 ? 1.f / (float)dg : 0.f;
        const float4* ptp = (const float4*)(p1t + (size_t)n * 12);
        float4 a0 = ptp[0], a1 = ptp[1], a2 = ptp[2];
        float pt[12] = {a0.x,a0.y,a0.z,a0.w, a1.x,a1.y,a1.z,a1.w, a2.x,a2.y,a2.z,a2.w};
        float h1[12];
        #pragma unroll
        for (int j = 0; j < 12; ++j) {
            float v = pt[j] + hacc[tid * 13 + j] * inv + b1[j];
            h1[j] = v > 0.f ? v : 0.f;
        }
        float oa[12], ob[12];
        #pragma unroll
        for (int co = 0; co < 12; ++co) {
            float A = 0.f, B = 0.f;
            #pragma unroll
            for (int k = 0; k < 12; ++k) {
                A += h1[k] * w2[k*12 + co];
                B += h1[k] * w2[(12+k)*12 + co];
            }
            oa[co] = A; ob[co] = B;
        }
        float4* ot = (float4*)(p2t + (size_t)n * 12);
        float4* ou = (float4*)(p2b + (size_t)n * 12);
        ot[0] = make_float4(oa[0],oa[1],oa[2],oa[3]);
        ot[1] = make_float4(oa[4],oa[5],oa[6],oa[7]);
        ot[2] = make_float4(oa[8],oa[9],oa[10],oa[11]);
        ou[0] = make_float4(ob[0],ob[1],ob[2],ob[3]);
        ou[1] = make_float4(ob[4],ob[5],ob[6],ob[7]);
        ou[2] = make_float4(ob[8],ob[9],ob[10],ob[11]);
    }
}

// ---------------- K5: fused gather2 + finalize2 (elementwise per channel-quad) -
__global__ void gather_fin2_kernel(const int* __restrict__ row_start,
                                   const ushort16* __restrict__ sorted_src,
                                   const float* __restrict__ p2t, const float* __restrict__ p2b,
                                   const float* __restrict__ b2eff, float* __restrict__ h2) {
    int t = blockIdx.x * blockDim.x + threadIdx.x;
    if (t >= NN * 3) return;
    int n = t / 3, q = t - n * 3;
    int r0 = row_start[n], r1 = row_start[n + 1];
    float4 s = make_float4(0.f, 0.f, 0.f, 0.f);
    if (r0 < r1) {
        int sn = (int)sorted_src[r0];             // software-pipelined index
        for (int i = r0 + 1; i < r1; ++i) {
            int sn_next = (int)sorted_src[i];
            float4 v = ((const float4*)(p2b + (size_t)sn * 12))[q];
            s.x += v.x; s.y += v.y; s.z += v.z; s.w += v.w;
            sn = sn_next;
        }
        float4 v = ((const float4*)(p2b + (size_t)sn * 12))[q];
        s.x += v.x; s.y += v.y; s.z += v.z; s.w += v.w;
    }
    float inv = (r1 > r0) ? 1.f / (float)(r1 - r0) : 0.f;
    float4 pt = ((const float4*)(p2t + (size_t)n * 12))[q];
    const float* b2 = b2eff + q * 4;
    float4 o;
    o.x = pt.x + s.x * inv + b2[0]; o.x = o.x > 0.f ? o.x : 0.f;
    o.y = pt.y + s.y * inv + b2[1]; o.y = o.y > 0.f ? o.y : 0.f;
    o.z = pt.z + s.z * inv + b2[2]; o.z = o.z > 0.f ? o.z : 0.f;
    o.w = pt.w + s.w * inv + b2[3]; o.w = o.w > 0.f ? o.w : 0.f;
    ((float4*)(h2 + (size_t)n * 12))[q] = o;
}

// ---------------- K6: per-graph segment mean of h2 + @Wc + bc ------------------
__global__ void graph_kernel(const float* __restrict__ h2, const int* __restrict__ gstart,
                             const float* __restrict__ Wc, const float* __restrict__ bc,
                             float* __restrict__ out) {
    __shared__ float sh[252];
    __shared__ float hg[12];
    int g = blockIdx.x;
    int r0 = gstart[g], r1 = gstart[g + 1];
    int tid = threadIdx.x;
    int group = tid / 12, ch = tid - group * 12;
    if (tid < 252) {
        float s = 0.f;
        for (int n = r0 + group; n < r1; n += 21) s += h2[(size_t)n * 12 + ch];
        sh[tid] = s;
    }
    __syncthreads();
    if (tid < 12) {
        float tot = 0.f;
        #pragma unroll
        for (int k = 0; k < 21; ++k) tot += sh[k*12 + tid];
        int cntn = r1 - r0;
        hg[tid] = cntn > 0 ? tot / (float)cntn : 0.f;
    }
    __syncthreads();
    if (tid < 10) {
        float o = bc[tid];
        #pragma unroll
        for (int j = 0; j < 12; ++j) o += hg[j] * Wc[j*10 + tid];
        out[g*10 + tid] = o;
    }
}

extern "C" void kernel_launch(void* const* d_in, const int* in_sizes, int n_in,
                              void* d_out, int out_size, void* d_ws, size_t ws_size,
                              hipStream_t stream) {
    const float* h   = (const float*)d_in[0];
    const int* src   = (const int*)d_in[1];
    const int* dst   = (const int*)d_in[2];
    const int* gid   = (const int*)d_in[3];
    const float* W1a = (const float*)d_in[4];
    const float* b1a = (const float*)d_in[5];
    const float* W1b = (const float*)d_in[6];
    const float* b1b = (const float*)d_in[7];
    const float* W2a = (const float*)d_in[8];
    const float* b2a = (const float*)d_in[9];
    const float* W2b = (const float*)d_in[10];
    const float* b2b = (const float*)d_in[11];
    const float* Wc  = (const float*)d_in[12];
    const float* bc  = (const float*)d_in[13];
    float* out = (float*)d_out;

    float* ws = (float*)d_ws;
    float* W1eff = ws;                          // 3072
    float* b1eff = ws + 3072;                   // 12
    float* W2eff = ws + 3084;                   // 288
    float* b2eff = ws + 3372;                   // 12
    float* p1t   = ws + 1000000;                // 600000
    float* p1b   = ws + 1600000;                // 600000
    float* p2t   = ws + 2200000;                // 600000
    float* p2b   = ws + 2800000;                // 600000
    float* h2    = ws + 3400000;                // 600000
    uint32* pairs = (uint32*)(ws + 4000000);    // 800000 x 4B
    int*   hist_mat   = (int*)(ws + 4800000);   // 76636
    int*   off_mat    = (int*)(ws + 4880000);   // 76636
    ushort16* sorted_src = (ushort16*)(ws + 4960000);  // 800000 x 2B
    int*   row_start  = (int*)(ws + 5360000);   // 50001
    int*   btot       = (int*)(ws + 5420000);   // 196
    int*   gstart     = (int*)(ws + 5424000);   // 513  -> total ~21.7 MB

    prep_kernel<<<B1_BLOCKS + 14 + 196, 256, 0, stream>>>(
        dst, hist_mat, W1a, b1a, W1b, b1b, W2a, b2a, W2b, b2b,
        W1eff, b1eff, W2eff, b2eff, gid, gstart);

    offsp1_kernel<<<NB, 768, 0, stream>>>(hist_mat, off_mat, btot, h, W1eff, p1t, p1b);

    place_pairs_kernel<<<B1_BLOCKS, 256, 0, stream>>>(src, dst, off_mat, btot, pairs);

    fine_gf1_kernel<<<NB, 768, 0, stream>>>(pairs, btot, p1t, p1b, b1eff, W2eff,
                                            row_start, sorted_src, p2t, p2b);

    gather_fin2_kernel<<<(NN * 3 + 255) / 256, 256, 0, stream>>>(row_start, sorted_src,
                                                                 p2t, p2b, b2eff, h2);

    graph_kernel<<<NG, 256, 0, stream>>>(h2, gstart, Wc, bc, out);
}